// Round 9
// baseline (203.937 us; speedup 1.0000x reference)
//
#include <hip/hip_runtime.h>
#include <hip/hip_bf16.h>
#include <math.h>

typedef __attribute__((ext_vector_type(8))) short short8;
typedef __attribute__((ext_vector_type(8))) unsigned short us8;
typedef __attribute__((ext_vector_type(4))) float f32x4;

#define TBK 128

__device__ inline unsigned short f2bf(float f) {
    unsigned int u = __float_as_uint(f);
    unsigned int r = u + 0x7fffu + ((u >> 16) & 1u);   // RTNE
    return (unsigned short)(r >> 16);
}
__device__ inline float bf2f(unsigned short h) {
    return __uint_as_float(((unsigned int)h) << 16);
}

// async global->LDS, 16 B per lane; LDS dest = wave-uniform base + lane*16 (linear!)
__device__ __forceinline__ void gld16(const unsigned short* g, unsigned short* l) {
    __builtin_amdgcn_global_load_lds(
        (const __attribute__((address_space(1))) unsigned int*)g,
        (__attribute__((address_space(3))) unsigned int*)l, 16, 0, 0);
}

// ---------------- fused prep: convX (-> Xh[10000][896] bf16, zero-pad) + W1/W2 transpose + deg/CSR ----

__global__ __launch_bounds__(256) void prep_kernel(
    const float* __restrict__ x, unsigned short* __restrict__ Xh,
    const float* __restrict__ W1, unsigned short* __restrict__ W1hT,
    const float* __restrict__ W2, unsigned short* __restrict__ W2hT,
    const int* __restrict__ src, const int* __restrict__ dst,
    int* __restrict__ deg, int* __restrict__ csr_pad,
    int M, int K1, int Kp1, int H, int E,
    int bX, int bT1, int bT2)
{
    __shared__ unsigned short T[64][65];
    const int b = blockIdx.x;
    const int tid = threadIdx.x;
    if (b < bX) {
        // X convert, 4 elems/thread (K1 % 4 == 0; k >= K1 zero-pad to Kp1)
        int id = b * 256 + tid;                 // ushort4 index
        int kp4 = Kp1 >> 2;                     // 224
        int k14 = K1 >> 2;                      // 196
        if (id < M * kp4) {
            int r = id / kp4;
            int k4 = id - r * kp4;
            ushort4 o;
            if (k4 < k14) {
                float4 v = *(const float4*)&x[(size_t)r * K1 + k4 * 4];
                o.x = f2bf(v.x); o.y = f2bf(v.y); o.z = f2bf(v.z); o.w = f2bf(v.w);
            } else {
                o.x = o.y = o.z = o.w = 0;
            }
            *(ushort4*)&Xh[(size_t)r * Kp1 + k4 * 4] = o;
        }
    } else if (b < bX + bT1) {
        // W1 [784,512] -> W1hT [512,896] (zero-pad k >= 784)
        int t = b - bX;
        int kt = t >> 3;              // 14 k-tiles
        int nt = t & 7;               // 8 n-tiles
        int k0 = kt * 64, n0 = nt * 64;
        int nl = tid & 63, kl0 = tid >> 6;
#pragma unroll
        for (int j = 0; j < 16; j++) {
            int k = k0 + kl0 + j * 4;
            float v = (k < K1) ? W1[(size_t)k * H + n0 + nl] : 0.f;
            T[kl0 + j * 4][nl] = f2bf(v);
        }
        __syncthreads();
        int kl = tid & 63, nl0 = tid >> 6;
#pragma unroll
        for (int j = 0; j < 16; j++) {
            int k = k0 + kl;
            if (k < Kp1) W1hT[(size_t)(n0 + nl0 + j * 4) * Kp1 + k] = T[kl][nl0 + j * 4];
        }
    } else if (b < bX + bT1 + bT2) {
        // W2 [512,512] -> W2hT [512,512]
        int t = b - bX - bT1;
        int kt = t >> 3, nt = t & 7;
        int k0 = kt * 64, n0 = nt * 64;
        int nl = tid & 63, kl0 = tid >> 6;
#pragma unroll
        for (int j = 0; j < 16; j++) {
            int k = k0 + kl0 + j * 4;
            T[kl0 + j * 4][nl] = f2bf(W2[(size_t)k * H + n0 + nl]);
        }
        __syncthreads();
        int kl = tid & 63, nl0 = tid >> 6;
#pragma unroll
        for (int j = 0; j < 16; j++)
            W2hT[(size_t)(n0 + nl0 + j * 4) * H + k0 + kl] = T[kl][nl0 + j * 4];
    } else {
        int e = (b - bX - bT1 - bT2) * 256 + tid;
        if (e < E) {
            int d = dst[e];
            int pos = atomicAdd(&deg[d], 1) & 63;   // bucket CSR; P(deg>64) ~ 1e-14
            csr_pad[d * 64 + pos] = src[e];
        }
    }
}

// ---------------- MFMA GEMM: 64x64 tile, TBK=128, double-buffered 2-phase pipeline ----------------
// T3 minimum recipe: stage NEXT K-tile before computing current; ONE barrier per step.
// The barrier's implicit vmcnt(0) drain now happens after ~600cy of compute covered the latency.
// Swizzle (rule #21): gld16 dest linear; per-lane global SOURCE slot = lslot ^ (ldsrow&7);
// ds_read applies same XOR -> 2-way banks (free).

__global__ __launch_bounds__(256, 2) void gemm_mfma_kernel(
    const unsigned short* __restrict__ AhG,
    const unsigned short* __restrict__ WhT,
    unsigned short* __restrict__ Hb, int M, int Kp, int gemmBlocks,
    const int* __restrict__ deg, float* __restrict__ dinv, int nNodes)
{
    const int blk = blockIdx.x;
    if (blk >= gemmBlocks) {
        int i = (blk - gemmBlocks) * 256 + threadIdx.x;
        if (i < nNodes) dinv[i] = rsqrtf((float)deg[i] + 1.0f);
        return;
    }

    // XCD swizzle (gemmBlocks % 8 == 0): consecutive tiles share an A row-panel on one XCD
    const int chunk = gemmBlocks >> 3;
    const int t = (blk & 7) * chunk + (blk >> 3);
    const int tm = t >> 3;           // 8 col tiles (N=512/64)
    const int tn = t & 7;

    __shared__ unsigned short Ah[2][64 * TBK];   // 2 x 16 KB
    __shared__ unsigned short Bh[2][64 * TBK];   // 2 x 16 KB

    const int tid  = threadIdx.x;
    const int wave = tid >> 6;
    const int lane = tid & 63;
    const int quad = lane >> 4;
    const int l16  = lane & 15;
    const int row0 = tm * 64;
    const int col0 = tn * 64;
    const int wr = (wave >> 1) * 32;
    const int wc = (wave & 1) * 32;

    // staging: each wave stages 16 rows of A and B via 4 gld16 calls each (4 rows/call)
    const int lrow  = lane >> 4;       // 0..3 within a call
    const int lslot = lane & 15;       // 16-B slot within row
    const unsigned short* pA[4];
    const unsigned short* pB[4];
    int loff[4];
#pragma unroll
    for (int j = 0; j < 4; j++) {
        int rbase  = wave * 16 + j * 4;
        int ldsrow = rbase + lrow;                 // 0..63
        int xs     = lslot ^ (ldsrow & 7);         // swizzled source slot
        int ga = row0 + ldsrow; if (ga >= M) ga = M - 1;
        pA[j] = AhG + (size_t)ga * Kp + xs * 8;
        pB[j] = WhT + (size_t)(col0 + ldsrow) * Kp + xs * 8;
        loff[j] = rbase * TBK;
    }

    f32x4 acc[2][2];
#pragma unroll
    for (int b = 0; b < 2; b++)
#pragma unroll
        for (int c = 0; c < 2; c++) acc[b][c] = (f32x4){0.f, 0.f, 0.f, 0.f};

    const int nt = Kp / TBK;           // 7 (Kp=896) or 4 (Kp=512)

    // prologue: stage buffer 0 with K-tile 0
#pragma unroll
    for (int j = 0; j < 4; j++) gld16(pA[j], &Ah[0][loff[j]]);
#pragma unroll
    for (int j = 0; j < 4; j++) gld16(pB[j], &Bh[0][loff[j]]);

    int cur = 0;
    for (int step = 0; step < nt; step++) {
        __syncthreads();               // drains staging of buf[cur]; all waves done reading buf[cur^1]

        if (step + 1 < nt) {           // issue NEXT K-tile into the other buffer (hidden under compute)
            int k0 = (step + 1) * TBK;
#pragma unroll
            for (int j = 0; j < 4; j++) gld16(pA[j] + k0, &Ah[cur ^ 1][loff[j]]);
#pragma unroll
            for (int j = 0; j < 4; j++) gld16(pB[j] + k0, &Bh[cur ^ 1][loff[j]]);
        }

        short8 ah[2][4], bh[2][4];
#pragma unroll
        for (int b = 0; b < 2; b++) {
            int r = wr + b * 16 + l16;
#pragma unroll
            for (int sk = 0; sk < 4; sk++)
                ah[b][sk] = *(const short8*)&Ah[cur][r * TBK + ((sk * 4 + quad) ^ (r & 7)) * 8];
        }
#pragma unroll
        for (int c = 0; c < 2; c++) {
            int r = wc + c * 16 + l16;
#pragma unroll
            for (int sk = 0; sk < 4; sk++)
                bh[c][sk] = *(const short8*)&Bh[cur][r * TBK + ((sk * 4 + quad) ^ (r & 7)) * 8];
        }
#pragma unroll
        for (int sk = 0; sk < 4; sk++)
#pragma unroll
            for (int c = 0; c < 2; c++)
#pragma unroll
                for (int b = 0; b < 2; b++)
                    acc[b][c] = __builtin_amdgcn_mfma_f32_16x16x32_bf16(ah[b][sk], bh[c][sk], acc[b][c], 0, 0, 0);
        cur ^= 1;
    }

#pragma unroll
    for (int b = 0; b < 2; b++) {
#pragma unroll
        for (int c = 0; c < 2; c++) {
            int gc = col0 + wc + c * 16 + l16;
#pragma unroll
            for (int r = 0; r < 4; r++) {
                int gr = row0 + wr + b * 16 + quad * 4 + r;
                if (gr < M) Hb[(size_t)gr * 512 + gc] = f2bf(acc[b][c][r]);
            }
        }
    }
}

// ---------------- gather aggregation, F=512 (layer 1): wave per node, bucket CSR ----------------

__global__ __launch_bounds__(256) void gather512_kernel(
    const unsigned short* __restrict__ hb,
    unsigned short* __restrict__ out_h,
    const int* __restrict__ csr_pad, const int* __restrict__ deg,
    const float* __restrict__ dinv, const float* __restrict__ bias, int n)
{
    const int wv = threadIdx.x >> 6;
    const int lane = threadIdx.x & 63;
    const int node = blockIdx.x * 4 + wv;
    if (node >= n) return;
    const float di = dinv[node];
    const int fo = lane * 8;
    const int base = node * 64;
    const int cnt = min(deg[node], 64);

    us8 self = *(const us8*)&hb[(size_t)node * 512 + fo];
    float4 b0 = *(const float4*)&bias[fo];
    float4 b1 = *(const float4*)&bias[fo + 4];
    const float dd = di * di;
    float acc[8];
    acc[0] = dd * bf2f(self[0]) + b0.x;
    acc[1] = dd * bf2f(self[1]) + b0.y;
    acc[2] = dd * bf2f(self[2]) + b0.z;
    acc[3] = dd * bf2f(self[3]) + b0.w;
    acc[4] = dd * bf2f(self[4]) + b1.x;
    acc[5] = dd * bf2f(self[5]) + b1.y;
    acc[6] = dd * bf2f(self[6]) + b1.z;
    acc[7] = dd * bf2f(self[7]) + b1.w;

    int p = 0;
    for (; p + 7 < cnt; p += 8) {
        int s[8];
#pragma unroll
        for (int u = 0; u < 8; u++) s[u] = csr_pad[base + p + u];
        us8 r[8];
#pragma unroll
        for (int u = 0; u < 8; u++) r[u] = *(const us8*)&hb[(size_t)s[u] * 512 + fo];
        float w[8];
#pragma unroll
        for (int u = 0; u < 8; u++) w[u] = dinv[s[u]] * di;
#pragma unroll
        for (int i = 0; i < 8; i++) {
            float t = acc[i];
#pragma unroll
            for (int u = 0; u < 8; u++) t += w[u] * bf2f(r[u][i]);
            acc[i] = t;
        }
    }
    for (; p + 3 < cnt; p += 4) {
        int s0 = csr_pad[base + p], s1 = csr_pad[base + p + 1];
        int s2 = csr_pad[base + p + 2], s3 = csr_pad[base + p + 3];
        float w0 = dinv[s0] * di, w1 = dinv[s1] * di, w2 = dinv[s2] * di, w3 = dinv[s3] * di;
        us8 r0 = *(const us8*)&hb[(size_t)s0 * 512 + fo];
        us8 r1 = *(const us8*)&hb[(size_t)s1 * 512 + fo];
        us8 r2 = *(const us8*)&hb[(size_t)s2 * 512 + fo];
        us8 r3 = *(const us8*)&hb[(size_t)s3 * 512 + fo];
#pragma unroll
        for (int i = 0; i < 8; i++)
            acc[i] += w0 * bf2f(r0[i]) + w1 * bf2f(r1[i]) + w2 * bf2f(r2[i]) + w3 * bf2f(r3[i]);
    }
    for (; p < cnt; ++p) {
        int s = csr_pad[base + p];
        float w = dinv[s] * di;
        us8 r = *(const us8*)&hb[(size_t)s * 512 + fo];
#pragma unroll
        for (int i = 0; i < 8; i++) acc[i] += w * bf2f(r[i]);
    }

    us8 o;
#pragma unroll
    for (int i = 0; i < 8; i++) o[i] = f2bf(fmaxf(acc[i], 0.f));
    *(us8*)&out_h[(size_t)node * 512 + fo] = o;
}

// ---------------- gather F=512 (layer 2) + fused classifier ----------------

__global__ __launch_bounds__(256) void gather512c_kernel(
    const unsigned short* __restrict__ hb,
    const int* __restrict__ csr_pad, const int* __restrict__ deg,
    const float* __restrict__ dinv, const float* __restrict__ bias,
    const float* __restrict__ Wc, float* __restrict__ h3, int n)
{
    const int wv = threadIdx.x >> 6;
    const int lane = threadIdx.x & 63;
    const int node = blockIdx.x * 4 + wv;
    if (node >= n) return;
    const float di = dinv[node];
    const int fo = lane * 8;
    const int base = node * 64;
    const int cnt = min(deg[node], 64);

    us8 self = *(const us8*)&hb[(size_t)node * 512 + fo];
    float4 b0 = *(const float4*)&bias[fo];
    float4 b1 = *(const float4*)&bias[fo + 4];
    const float dd = di * di;
    float acc[8];
    acc[0] = dd * bf2f(self[0]) + b0.x;
    acc[1] = dd * bf2f(self[1]) + b0.y;
    acc[2] = dd * bf2f(self[2]) + b0.z;
    acc[3] = dd * bf2f(self[3]) + b0.w;
    acc[4] = dd * bf2f(self[4]) + b1.x;
    acc[5] = dd * bf2f(self[5]) + b1.y;
    acc[6] = dd * bf2f(self[6]) + b1.z;
    acc[7] = dd * bf2f(self[7]) + b1.w;

    int p = 0;
    for (; p + 7 < cnt; p += 8) {
        int s[8];
#pragma unroll
        for (int u = 0; u < 8; u++) s[u] = csr_pad[base + p + u];
        us8 r[8];
#pragma unroll
        for (int u = 0; u < 8; u++) r[u] = *(const us8*)&hb[(size_t)s[u] * 512 + fo];
        float w[8];
#pragma unroll
        for (int u = 0; u < 8; u++) w[u] = dinv[s[u]] * di;
#pragma unroll
        for (int i = 0; i < 8; i++) {
            float t = acc[i];
#pragma unroll
            for (int u = 0; u < 8; u++) t += w[u] * bf2f(r[u][i]);
            acc[i] = t;
        }
    }
    for (; p + 3 < cnt; p += 4) {
        int s0 = csr_pad[base + p], s1 = csr_pad[base + p + 1];
        int s2 = csr_pad[base + p + 2], s3 = csr_pad[base + p + 3];
        float w0 = dinv[s0] * di, w1 = dinv[s1] * di, w2 = dinv[s2] * di, w3 = dinv[s3] * di;
        us8 r0 = *(const us8*)&hb[(size_t)s0 * 512 + fo];
        us8 r1 = *(const us8*)&hb[(size_t)s1 * 512 + fo];
        us8 r2 = *(const us8*)&hb[(size_t)s2 * 512 + fo];
        us8 r3 = *(const us8*)&hb[(size_t)s3 * 512 + fo];
#pragma unroll
        for (int i = 0; i < 8; i++)
            acc[i] += w0 * bf2f(r0[i]) + w1 * bf2f(r1[i]) + w2 * bf2f(r2[i]) + w3 * bf2f(r3[i]);
    }
    for (; p < cnt; ++p) {
        int s = csr_pad[base + p];
        float w = dinv[s] * di;
        us8 r = *(const us8*)&hb[(size_t)s * 512 + fo];
#pragma unroll
        for (int i = 0; i < 8; i++) acc[i] += w * bf2f(r[i]);
    }

    // classifier: per-lane 8-feature slice x Wc rows fo..fo+7 (L1-resident, 8 B loads)
    float wcr[8][10];
#pragma unroll
    for (int i = 0; i < 8; i++) {
        const float2* wp = (const float2*)&Wc[(size_t)(fo + i) * 10];
#pragma unroll
        for (int j = 0; j < 5; j++) {
            float2 v = wp[j];
            wcr[i][2 * j] = v.x; wcr[i][2 * j + 1] = v.y;
        }
    }
    float pc[10];
#pragma unroll
    for (int c = 0; c < 10; c++) pc[c] = 0.f;
#pragma unroll
    for (int i = 0; i < 8; i++) {
        float r = fmaxf(acc[i], 0.f);
#pragma unroll
        for (int c = 0; c < 10; c++) pc[c] += r * wcr[i][c];
    }
#pragma unroll
    for (int c = 0; c < 10; c++) {
#pragma unroll
        for (int off = 1; off < 64; off <<= 1)
            pc[c] += __shfl_xor(pc[c], off);
    }
    if (lane == 0) {
#pragma unroll
        for (int c = 0; c < 10; c++) h3[(size_t)node * 10 + c] = pc[c];
    }
}

// ---------------- fused gather(F=10) + log_softmax: WAVE per node ----------------

__global__ __launch_bounds__(256) void gather10_softmax_kernel(
    const float* __restrict__ h3, float* __restrict__ out,
    const int* __restrict__ csr_pad, const int* __restrict__ deg,
    const float* __restrict__ dinv, const float* __restrict__ bc, int n)
{
    const int wv = threadIdx.x >> 6;
    const int lane = threadIdx.x & 63;
    const int node = blockIdx.x * 4 + wv;
    if (node >= n) return;

    const int eg = lane / 10;          // 0..5 (lane<60), 6 for lanes 60..63
    const int c  = lane - eg * 10;
    const bool active = lane < 60;
    const float di = dinv[node];
    const int base = node * 64;
    const int cnt = min(deg[node], 64);

    float acc = 0.f;
    if (active) {
        for (int p = eg; p < cnt; p += 6) {
            int s = csr_pad[base + p];
            acc += h3[(size_t)s * 10 + c] * dinv[s];
        }
        acc *= di;
    }
    // reduce eg-groups: lanes (c, c+10, ..., c+50) -> lane c
    acc += __shfl(acc, lane + 30);                         // lanes 0..29 pick up eg+3
    float t1 = __shfl(acc, lane + 10);
    float t2 = __shfl(acc, lane + 20);
    if (lane < 10) {
        acc = acc + t1 + t2 + h3[(size_t)node * 10 + c] * di * di + bc[c];
    }
    float vj[10];
#pragma unroll
    for (int j = 0; j < 10; j++) vj[j] = __shfl(acc, j);
    if (lane < 10) {
        float m = vj[0];
#pragma unroll
        for (int j = 1; j < 10; j++) m = fmaxf(m, vj[j]);
        float ssum = 0.f;
#pragma unroll
        for (int j = 0; j < 10; j++) ssum += __expf(vj[j] - m);
        out[(size_t)node * 10 + c] = acc - (m + __logf(ssum));
    }
}

// ---------------- launch ----------------

extern "C" void kernel_launch(void* const* d_in, const int* in_sizes, int n_in,
                              void* d_out, int out_size, void* d_ws, size_t ws_size,
                              hipStream_t stream)
{
    const float* x   = (const float*)d_in[0];
    const int*   ei  = (const int*)d_in[1];
    const float* W1  = (const float*)d_in[2];
    const float* b1  = (const float*)d_in[3];
    const float* W2  = (const float*)d_in[4];
    const float* b2  = (const float*)d_in[5];
    const float* Wc  = (const float*)d_in[6];
    const float* bc  = (const float*)d_in[7];
    float* out = (float*)d_out;

    const int IN_FEATS = 784;
    const int KP1 = 896;                    // 7 x 128
    const int H = 512;
    const int NC = 10;
    const int n = in_sizes[0] / IN_FEATS;   // 10000
    const int E = in_sizes[1] / 2;          // 160000
    const int* src = ei;
    const int* dst = ei + E;

    // workspace layout (~43 MB)
    char* ws = (char*)d_ws;
    unsigned short* Hb   = (unsigned short*)ws; ws += (size_t)n * H * sizeof(unsigned short);
    unsigned short* Xh   = (unsigned short*)ws; ws += (size_t)n * KP1 * sizeof(unsigned short);
    unsigned short* AhB  = (unsigned short*)ws; ws += (size_t)n * H * sizeof(unsigned short);
    unsigned short* W1hT = (unsigned short*)ws; ws += (size_t)KP1 * H * sizeof(unsigned short);
    unsigned short* W2hT = (unsigned short*)ws; ws += (size_t)H * H * sizeof(unsigned short);
    float* dinv      = (float*)ws;             ws += (size_t)n * sizeof(float);
    int*   deg       = (int*)ws;               ws += (size_t)n * sizeof(int);
    int*   csr_pad   = (int*)ws;               ws += (size_t)n * 64 * sizeof(int);
    float* h3        = (float*)ws;             ws += (size_t)n * NC * sizeof(float);

    hipMemsetAsync(deg, 0, (size_t)n * sizeof(int), stream);

    // ---- fused prep (X conv + W transposes + deg count + bucket-CSR fill) ----
    const int bX  = ((size_t)n * (KP1 / 4) + 255) / 256;   // 8750
    const int bT1 = ((KP1 + 63) / 64) * (H / 64);          // 112
    const int bT2 = (H / 64) * (H / 64);                   // 64
    const int bE  = (E + 255) / 256;                       // 625
    prep_kernel<<<bX + bT1 + bT2 + bE, 256, 0, stream>>>(
        x, Xh, W1, W1hT, W2, W2hT, src, dst, deg, csr_pad,
        n, IN_FEATS, KP1, H, E, bX, bT1, bT2);

    const int tiles_m = (n + 63) / 64;                      // 157
    const int gemmBlocks = tiles_m * 8;                     // 1256 (64x64 tiles, N=512)
    const int bN = (n + 255) / 256;                         // 40 dinv blocks

    // ---- layer 1 (+ dinv riding the dispatch) ----
    gemm_mfma_kernel<<<gemmBlocks + bN, 256, 0, stream>>>(
        Xh, W1hT, Hb, n, KP1, gemmBlocks, deg, dinv, n);
    gather512_kernel<<<(n + 3) / 4, 256, 0, stream>>>(Hb, AhB, csr_pad, deg, dinv, b1, n);

    // ---- layer 2 (+ fused classifier epilogue) ----
    gemm_mfma_kernel<<<gemmBlocks, 256, 0, stream>>>(
        AhB, W2hT, Hb, n, H, gemmBlocks, deg, dinv, 0);
    gather512c_kernel<<<(n + 3) / 4, 256, 0, stream>>>(Hb, csr_pad, deg, dinv, b2, Wc, h3, n);

    // ---- softmax layer ----
    gather10_softmax_kernel<<<(n + 3) / 4, 256, 0, stream>>>(h3, out, csr_pad, deg, dinv, bc, n);
}

// Round 10
// 195.612 us; speedup vs baseline: 1.0426x; 1.0426x over previous
//
#include <hip/hip_runtime.h>
#include <hip/hip_bf16.h>
#include <math.h>

typedef __attribute__((ext_vector_type(8))) short short8;
typedef __attribute__((ext_vector_type(8))) unsigned short us8;
typedef __attribute__((ext_vector_type(4))) float f32x4;

#define TBK 128

__device__ inline unsigned short f2bf(float f) {
    unsigned int u = __float_as_uint(f);
    unsigned int r = u + 0x7fffu + ((u >> 16) & 1u);   // RTNE
    return (unsigned short)(r >> 16);
}
__device__ inline float bf2f(unsigned short h) {
    return __uint_as_float(((unsigned int)h) << 16);
}

// async global->LDS, 16 B per lane; LDS dest = wave-uniform base + lane*16 (linear!)
__device__ __forceinline__ void gld16(const unsigned short* g, unsigned short* l) {
    __builtin_amdgcn_global_load_lds(
        (const __attribute__((address_space(1))) unsigned int*)g,
        (__attribute__((address_space(3))) unsigned int*)l, 16, 0, 0);
}

// ---------------- fused prep: convX (-> Xh[10000][896] bf16, zero-pad) + W1/W2 transpose + deg/CSR ----

__global__ __launch_bounds__(256) void prep_kernel(
    const float* __restrict__ x, unsigned short* __restrict__ Xh,
    const float* __restrict__ W1, unsigned short* __restrict__ W1hT,
    const float* __restrict__ W2, unsigned short* __restrict__ W2hT,
    const int* __restrict__ src, const int* __restrict__ dst,
    int* __restrict__ deg, int* __restrict__ csr_pad,
    int M, int K1, int Kp1, int H, int E,
    int bX, int bT1, int bT2)
{
    __shared__ unsigned short T[64][65];
    const int b = blockIdx.x;
    const int tid = threadIdx.x;
    if (b < bX) {
        // X convert, 4 elems/thread (K1 % 4 == 0; k >= K1 zero-pad to Kp1)
        int id = b * 256 + tid;                 // ushort4 index
        int kp4 = Kp1 >> 2;                     // 224
        int k14 = K1 >> 2;                      // 196
        if (id < M * kp4) {
            int r = id / kp4;
            int k4 = id - r * kp4;
            ushort4 o;
            if (k4 < k14) {
                float4 v = *(const float4*)&x[(size_t)r * K1 + k4 * 4];
                o.x = f2bf(v.x); o.y = f2bf(v.y); o.z = f2bf(v.z); o.w = f2bf(v.w);
            } else {
                o.x = o.y = o.z = o.w = 0;
            }
            *(ushort4*)&Xh[(size_t)r * Kp1 + k4 * 4] = o;
        }
    } else if (b < bX + bT1) {
        // W1 [784,512] -> W1hT [512,896] (zero-pad k >= 784)
        int t = b - bX;
        int kt = t >> 3;              // 14 k-tiles
        int nt = t & 7;               // 8 n-tiles
        int k0 = kt * 64, n0 = nt * 64;
        int nl = tid & 63, kl0 = tid >> 6;
#pragma unroll
        for (int j = 0; j < 16; j++) {
            int k = k0 + kl0 + j * 4;
            float v = (k < K1) ? W1[(size_t)k * H + n0 + nl] : 0.f;
            T[kl0 + j * 4][nl] = f2bf(v);
        }
        __syncthreads();
        int kl = tid & 63, nl0 = tid >> 6;
#pragma unroll
        for (int j = 0; j < 16; j++) {
            int k = k0 + kl;
            if (k < Kp1) W1hT[(size_t)(n0 + nl0 + j * 4) * Kp1 + k] = T[kl][nl0 + j * 4];
        }
    } else if (b < bX + bT1 + bT2) {
        // W2 [512,512] -> W2hT [512,512]
        int t = b - bX - bT1;
        int kt = t >> 3, nt = t & 7;
        int k0 = kt * 64, n0 = nt * 64;
        int nl = tid & 63, kl0 = tid >> 6;
#pragma unroll
        for (int j = 0; j < 16; j++) {
            int k = k0 + kl0 + j * 4;
            T[kl0 + j * 4][nl] = f2bf(W2[(size_t)k * H + n0 + nl]);
        }
        __syncthreads();
        int kl = tid & 63, nl0 = tid >> 6;
#pragma unroll
        for (int j = 0; j < 16; j++)
            W2hT[(size_t)(n0 + nl0 + j * 4) * H + k0 + kl] = T[kl][nl0 + j * 4];
    } else {
        int e = (b - bX - bT1 - bT2) * 256 + tid;
        if (e < E) {
            int d = dst[e];
            int pos = atomicAdd(&deg[d], 1) & 63;   // bucket CSR; P(deg>64) ~ 1e-14
            csr_pad[d * 64 + pos] = src[e];
        }
    }
}

// ---------------- MFMA GEMM: 64x64 tile, TBK=128, XOR-swizzled LDS, gld16 both operands ----------------
// Swizzle (rule #21): gld16 dest linear; per-lane global SOURCE slot = lslot ^ (ldsrow&7);
// ds_read applies same XOR -> 2-way banks (free). 7 (Kp=896) or 4 (Kp=512) K-steps.

__global__ __launch_bounds__(256, 4) void gemm_mfma_kernel(
    const unsigned short* __restrict__ AhG,
    const unsigned short* __restrict__ WhT,
    unsigned short* __restrict__ Hb, int M, int Kp, int gemmBlocks,
    const int* __restrict__ deg, float* __restrict__ dinv, int nNodes)
{
    const int blk = blockIdx.x;
    if (blk >= gemmBlocks) {
        int i = (blk - gemmBlocks) * 256 + threadIdx.x;
        if (i < nNodes) dinv[i] = rsqrtf((float)deg[i] + 1.0f);
        return;
    }

    // XCD swizzle (gemmBlocks % 8 == 0): consecutive tiles share an A row-panel on one XCD
    const int chunk = gemmBlocks >> 3;
    const int t = (blk & 7) * chunk + (blk >> 3);
    const int tm = t >> 3;           // 8 col tiles (N=512/64)
    const int tn = t & 7;

    __shared__ unsigned short Ah[64 * TBK];   // 16 KB
    __shared__ unsigned short Bh[64 * TBK];   // 16 KB

    const int tid  = threadIdx.x;
    const int wave = tid >> 6;
    const int lane = tid & 63;
    const int quad = lane >> 4;
    const int l16  = lane & 15;
    const int row0 = tm * 64;
    const int col0 = tn * 64;
    const int wr = (wave >> 1) * 32;
    const int wc = (wave & 1) * 32;

    // staging: each wave stages 16 rows of A and B via 4 gld16 calls each (4 rows/call)
    const int lrow  = lane >> 4;       // 0..3 within a call
    const int lslot = lane & 15;       // 16-B slot within row
    const unsigned short* pA[4];
    const unsigned short* pB[4];
    unsigned short* dA[4];
    unsigned short* dB[4];
#pragma unroll
    for (int j = 0; j < 4; j++) {
        int rbase  = wave * 16 + j * 4;
        int ldsrow = rbase + lrow;                 // 0..63
        int xs     = lslot ^ (ldsrow & 7);         // swizzled source slot
        int ga = row0 + ldsrow; if (ga >= M) ga = M - 1;
        pA[j] = AhG + (size_t)ga * Kp + xs * 8;
        pB[j] = WhT + (size_t)(col0 + ldsrow) * Kp + xs * 8;
        dA[j] = &Ah[rbase * TBK];
        dB[j] = &Bh[rbase * TBK];
    }

    f32x4 acc[2][2];
#pragma unroll
    for (int b = 0; b < 2; b++)
#pragma unroll
        for (int c = 0; c < 2; c++) acc[b][c] = (f32x4){0.f, 0.f, 0.f, 0.f};

    for (int k0 = 0; k0 < Kp; k0 += TBK) {
#pragma unroll
        for (int j = 0; j < 4; j++) gld16(pA[j] + k0, dA[j]);
#pragma unroll
        for (int j = 0; j < 4; j++) gld16(pB[j] + k0, dB[j]);
        __syncthreads();

        short8 ah[2][4], bh[2][4];
#pragma unroll
        for (int b = 0; b < 2; b++) {
            int r = wr + b * 16 + l16;
#pragma unroll
            for (int sk = 0; sk < 4; sk++)
                ah[b][sk] = *(const short8*)&Ah[r * TBK + ((sk * 4 + quad) ^ (r & 7)) * 8];
        }
#pragma unroll
        for (int c = 0; c < 2; c++) {
            int r = wc + c * 16 + l16;
#pragma unroll
            for (int sk = 0; sk < 4; sk++)
                bh[c][sk] = *(const short8*)&Bh[r * TBK + ((sk * 4 + quad) ^ (r & 7)) * 8];
        }
#pragma unroll
        for (int sk = 0; sk < 4; sk++)
#pragma unroll
            for (int c = 0; c < 2; c++)
#pragma unroll
                for (int b = 0; b < 2; b++)
                    acc[b][c] = __builtin_amdgcn_mfma_f32_16x16x32_bf16(ah[b][sk], bh[c][sk], acc[b][c], 0, 0, 0);
        __syncthreads();
    }

#pragma unroll
    for (int b = 0; b < 2; b++) {
#pragma unroll
        for (int c = 0; c < 2; c++) {
            int gc = col0 + wc + c * 16 + l16;
#pragma unroll
            for (int r = 0; r < 4; r++) {
                int gr = row0 + wr + b * 16 + quad * 4 + r;
                if (gr < M) Hb[(size_t)gr * 512 + gc] = f2bf(acc[b][c][r]);
            }
        }
    }
}

// ---------------- gather aggregation, F=512 (layer 1): wave per node, bucket CSR ----------------

__global__ __launch_bounds__(256) void gather512_kernel(
    const unsigned short* __restrict__ hb,
    unsigned short* __restrict__ out_h,
    const int* __restrict__ csr_pad, const int* __restrict__ deg,
    const float* __restrict__ dinv, const float* __restrict__ bias, int n)
{
    const int wv = threadIdx.x >> 6;
    const int lane = threadIdx.x & 63;
    const int node = blockIdx.x * 4 + wv;
    if (node >= n) return;
    const float di = dinv[node];
    const int fo = lane * 8;
    const int base = node * 64;
    const int cnt = min(deg[node], 64);

    us8 self = *(const us8*)&hb[(size_t)node * 512 + fo];
    float4 b0 = *(const float4*)&bias[fo];
    float4 b1 = *(const float4*)&bias[fo + 4];
    const float dd = di * di;
    float acc[8];
    acc[0] = dd * bf2f(self[0]) + b0.x;
    acc[1] = dd * bf2f(self[1]) + b0.y;
    acc[2] = dd * bf2f(self[2]) + b0.z;
    acc[3] = dd * bf2f(self[3]) + b0.w;
    acc[4] = dd * bf2f(self[4]) + b1.x;
    acc[5] = dd * bf2f(self[5]) + b1.y;
    acc[6] = dd * bf2f(self[6]) + b1.z;
    acc[7] = dd * bf2f(self[7]) + b1.w;

    int p = 0;
    for (; p + 7 < cnt; p += 8) {
        int s[8];
#pragma unroll
        for (int u = 0; u < 8; u++) s[u] = csr_pad[base + p + u];
        us8 r[8];
#pragma unroll
        for (int u = 0; u < 8; u++) r[u] = *(const us8*)&hb[(size_t)s[u] * 512 + fo];
        float w[8];
#pragma unroll
        for (int u = 0; u < 8; u++) w[u] = dinv[s[u]] * di;
#pragma unroll
        for (int i = 0; i < 8; i++) {
            float t = acc[i];
#pragma unroll
            for (int u = 0; u < 8; u++) t += w[u] * bf2f(r[u][i]);
            acc[i] = t;
        }
    }
    for (; p + 3 < cnt; p += 4) {
        int s0 = csr_pad[base + p], s1 = csr_pad[base + p + 1];
        int s2 = csr_pad[base + p + 2], s3 = csr_pad[base + p + 3];
        float w0 = dinv[s0] * di, w1 = dinv[s1] * di, w2 = dinv[s2] * di, w3 = dinv[s3] * di;
        us8 r0 = *(const us8*)&hb[(size_t)s0 * 512 + fo];
        us8 r1 = *(const us8*)&hb[(size_t)s1 * 512 + fo];
        us8 r2 = *(const us8*)&hb[(size_t)s2 * 512 + fo];
        us8 r3 = *(const us8*)&hb[(size_t)s3 * 512 + fo];
#pragma unroll
        for (int i = 0; i < 8; i++)
            acc[i] += w0 * bf2f(r0[i]) + w1 * bf2f(r1[i]) + w2 * bf2f(r2[i]) + w3 * bf2f(r3[i]);
    }
    for (; p < cnt; ++p) {
        int s = csr_pad[base + p];
        float w = dinv[s] * di;
        us8 r = *(const us8*)&hb[(size_t)s * 512 + fo];
#pragma unroll
        for (int i = 0; i < 8; i++) acc[i] += w * bf2f(r[i]);
    }

    us8 o;
#pragma unroll
    for (int i = 0; i < 8; i++) o[i] = f2bf(fmaxf(acc[i], 0.f));
    *(us8*)&out_h[(size_t)node * 512 + fo] = o;
}

// ---------------- gather F=512 (layer 2) + fused classifier ----------------

__global__ __launch_bounds__(256) void gather512c_kernel(
    const unsigned short* __restrict__ hb,
    const int* __restrict__ csr_pad, const int* __restrict__ deg,
    const float* __restrict__ dinv, const float* __restrict__ bias,
    const float* __restrict__ Wc, float* __restrict__ h3, int n)
{
    const int wv = threadIdx.x >> 6;
    const int lane = threadIdx.x & 63;
    const int node = blockIdx.x * 4 + wv;
    if (node >= n) return;
    const float di = dinv[node];
    const int fo = lane * 8;
    const int base = node * 64;
    const int cnt = min(deg[node], 64);

    us8 self = *(const us8*)&hb[(size_t)node * 512 + fo];
    float4 b0 = *(const float4*)&bias[fo];
    float4 b1 = *(const float4*)&bias[fo + 4];
    const float dd = di * di;
    float acc[8];
    acc[0] = dd * bf2f(self[0]) + b0.x;
    acc[1] = dd * bf2f(self[1]) + b0.y;
    acc[2] = dd * bf2f(self[2]) + b0.z;
    acc[3] = dd * bf2f(self[3]) + b0.w;
    acc[4] = dd * bf2f(self[4]) + b1.x;
    acc[5] = dd * bf2f(self[5]) + b1.y;
    acc[6] = dd * bf2f(self[6]) + b1.z;
    acc[7] = dd * bf2f(self[7]) + b1.w;

    int p = 0;
    for (; p + 7 < cnt; p += 8) {
        int s[8];
#pragma unroll
        for (int u = 0; u < 8; u++) s[u] = csr_pad[base + p + u];
        us8 r[8];
#pragma unroll
        for (int u = 0; u < 8; u++) r[u] = *(const us8*)&hb[(size_t)s[u] * 512 + fo];
        float w[8];
#pragma unroll
        for (int u = 0; u < 8; u++) w[u] = dinv[s[u]] * di;
#pragma unroll
        for (int i = 0; i < 8; i++) {
            float t = acc[i];
#pragma unroll
            for (int u = 0; u < 8; u++) t += w[u] * bf2f(r[u][i]);
            acc[i] = t;
        }
    }
    for (; p + 3 < cnt; p += 4) {
        int s0 = csr_pad[base + p], s1 = csr_pad[base + p + 1];
        int s2 = csr_pad[base + p + 2], s3 = csr_pad[base + p + 3];
        float w0 = dinv[s0] * di, w1 = dinv[s1] * di, w2 = dinv[s2] * di, w3 = dinv[s3] * di;
        us8 r0 = *(const us8*)&hb[(size_t)s0 * 512 + fo];
        us8 r1 = *(const us8*)&hb[(size_t)s1 * 512 + fo];
        us8 r2 = *(const us8*)&hb[(size_t)s2 * 512 + fo];
        us8 r3 = *(const us8*)&hb[(size_t)s3 * 512 + fo];
#pragma unroll
        for (int i = 0; i < 8; i++)
            acc[i] += w0 * bf2f(r0[i]) + w1 * bf2f(r1[i]) + w2 * bf2f(r2[i]) + w3 * bf2f(r3[i]);
    }
    for (; p < cnt; ++p) {
        int s = csr_pad[base + p];
        float w = dinv[s] * di;
        us8 r = *(const us8*)&hb[(size_t)s * 512 + fo];
#pragma unroll
        for (int i = 0; i < 8; i++) acc[i] += w * bf2f(r[i]);
    }

    // classifier: per-lane 8-feature slice x Wc rows fo..fo+7 (L1-resident, 8 B loads)
    float wcr[8][10];
#pragma unroll
    for (int i = 0; i < 8; i++) {
        const float2* wp = (const float2*)&Wc[(size_t)(fo + i) * 10];
#pragma unroll
        for (int j = 0; j < 5; j++) {
            float2 v = wp[j];
            wcr[i][2 * j] = v.x; wcr[i][2 * j + 1] = v.y;
        }
    }
    float pc[10];
#pragma unroll
    for (int c = 0; c < 10; c++) pc[c] = 0.f;
#pragma unroll
    for (int i = 0; i < 8; i++) {
        float r = fmaxf(acc[i], 0.f);
#pragma unroll
        for (int c = 0; c < 10; c++) pc[c] += r * wcr[i][c];
    }
#pragma unroll
    for (int c = 0; c < 10; c++) {
#pragma unroll
        for (int off = 1; off < 64; off <<= 1)
            pc[c] += __shfl_xor(pc[c], off);
    }
    if (lane == 0) {
#pragma unroll
        for (int c = 0; c < 10; c++) h3[(size_t)node * 10 + c] = pc[c];
    }
}

// ---------------- fused gather(F=10) + log_softmax: WAVE per node ----------------

__global__ __launch_bounds__(256) void gather10_softmax_kernel(
    const float* __restrict__ h3, float* __restrict__ out,
    const int* __restrict__ csr_pad, const int* __restrict__ deg,
    const float* __restrict__ dinv, const float* __restrict__ bc, int n)
{
    const int wv = threadIdx.x >> 6;
    const int lane = threadIdx.x & 63;
    const int node = blockIdx.x * 4 + wv;
    if (node >= n) return;

    const int eg = lane / 10;          // 0..5 (lane<60), 6 for lanes 60..63
    const int c  = lane - eg * 10;
    const bool active = lane < 60;
    const float di = dinv[node];
    const int base = node * 64;
    const int cnt = min(deg[node], 64);

    float acc = 0.f;
    if (active) {
        for (int p = eg; p < cnt; p += 6) {
            int s = csr_pad[base + p];
            acc += h3[(size_t)s * 10 + c] * dinv[s];
        }
        acc *= di;
    }
    // reduce eg-groups: lanes (c, c+10, ..., c+50) -> lane c
    acc += __shfl(acc, lane + 30);                         // lanes 0..29 pick up eg+3
    float t1 = __shfl(acc, lane + 10);
    float t2 = __shfl(acc, lane + 20);
    if (lane < 10) {
        acc = acc + t1 + t2 + h3[(size_t)node * 10 + c] * di * di + bc[c];
    }
    float vj[10];
#pragma unroll
    for (int j = 0; j < 10; j++) vj[j] = __shfl(acc, j);
    if (lane < 10) {
        float m = vj[0];
#pragma unroll
        for (int j = 1; j < 10; j++) m = fmaxf(m, vj[j]);
        float ssum = 0.f;
#pragma unroll
        for (int j = 0; j < 10; j++) ssum += __expf(vj[j] - m);
        out[(size_t)node * 10 + c] = acc - (m + __logf(ssum));
    }
}

// ---------------- launch ----------------

extern "C" void kernel_launch(void* const* d_in, const int* in_sizes, int n_in,
                              void* d_out, int out_size, void* d_ws, size_t ws_size,
                              hipStream_t stream)
{
    const float* x   = (const float*)d_in[0];
    const int*   ei  = (const int*)d_in[1];
    const float* W1  = (const float*)d_in[2];
    const float* b1  = (const float*)d_in[3];
    const float* W2  = (const float*)d_in[4];
    const float* b2  = (const float*)d_in[5];
    const float* Wc  = (const float*)d_in[6];
    const float* bc  = (const float*)d_in[7];
    float* out = (float*)d_out;

    const int IN_FEATS = 784;
    const int KP1 = 896;                    // 7 x 128
    const int H = 512;
    const int NC = 10;
    const int n = in_sizes[0] / IN_FEATS;   // 10000
    const int E = in_sizes[1] / 2;          // 160000
    const int* src = ei;
    const int* dst = ei + E;

    // workspace layout (~43 MB)
    char* ws = (char*)d_ws;
    unsigned short* Hb   = (unsigned short*)ws; ws += (size_t)n * H * sizeof(unsigned short);
    unsigned short* Xh   = (unsigned short*)ws; ws += (size_t)n * KP1 * sizeof(unsigned short);
    unsigned short* AhB  = (unsigned short*)ws; ws += (size_t)n * H * sizeof(unsigned short);
    unsigned short* W1hT = (unsigned short*)ws; ws += (size_t)KP1 * H * sizeof(unsigned short);
    unsigned short* W2hT = (unsigned short*)ws; ws += (size_t)H * H * sizeof(unsigned short);
    float* dinv      = (float*)ws;             ws += (size_t)n * sizeof(float);
    int*   deg       = (int*)ws;               ws += (size_t)n * sizeof(int);
    int*   csr_pad   = (int*)ws;               ws += (size_t)n * 64 * sizeof(int);
    float* h3        = (float*)ws;             ws += (size_t)n * NC * sizeof(float);

    hipMemsetAsync(deg, 0, (size_t)n * sizeof(int), stream);

    // ---- fused prep (X conv + W transposes + deg count + bucket-CSR fill) ----
    const int bX  = ((size_t)n * (KP1 / 4) + 255) / 256;   // 8750
    const int bT1 = ((KP1 + 63) / 64) * (H / 64);          // 112
    const int bT2 = (H / 64) * (H / 64);                   // 64
    const int bE  = (E + 255) / 256;                       // 625
    prep_kernel<<<bX + bT1 + bT2 + bE, 256, 0, stream>>>(
        x, Xh, W1, W1hT, W2, W2hT, src, dst, deg, csr_pad,
        n, IN_FEATS, KP1, H, E, bX, bT1, bT2);

    const int tiles_m = (n + 63) / 64;                      // 157
    const int gemmBlocks = tiles_m * 8;                     // 1256 (64x64 tiles, N=512)
    const int bN = (n + 255) / 256;                         // 40 dinv blocks

    // ---- layer 1 (+ dinv riding the dispatch) ----
    gemm_mfma_kernel<<<gemmBlocks + bN, 256, 0, stream>>>(
        Xh, W1hT, Hb, n, KP1, gemmBlocks, deg, dinv, n);
    gather512_kernel<<<(n + 3) / 4, 256, 0, stream>>>(Hb, AhB, csr_pad, deg, dinv, b1, n);

    // ---- layer 2 (+ fused classifier epilogue) ----
    gemm_mfma_kernel<<<gemmBlocks, 256, 0, stream>>>(
        AhB, W2hT, Hb, n, H, gemmBlocks, deg, dinv, 0);
    gather512c_kernel<<<(n + 3) / 4, 256, 0, stream>>>(Hb, csr_pad, deg, dinv, b2, Wc, h3, n);

    // ---- softmax layer ----
    gather10_softmax_kernel<<<(n + 3) / 4, 256, 0, stream>>>(h3, out, csr_pad, deg, dinv, bc, n);
}